// Round 13
// baseline (811.002 us; speedup 1.0000x reference)
//
#include <hip/hip_runtime.h>
#include <hip/hip_bf16.h>

typedef __attribute__((ext_vector_type(4))) int i32x4;

#define TOK   4096
#define OUTF  4096
#define INF   4096
#define KE    4160   // 4096 main + 64 lora block (16 used + 48 zero) -> 65 K-tiles of 64
#define NT    65
#define RANKD 16

#define VMCNT(n) asm volatile("s_waitcnt vmcnt(" #n ")" ::: "memory")
#define SCHED0   __builtin_amdgcn_sched_barrier(0)
#define BAR      __builtin_amdgcn_s_barrier()

static __device__ __forceinline__ void gload_lds16(const void* g, void* l) {
  __builtin_amdgcn_global_load_lds(
      (const __attribute__((address_space(1))) void*)g,
      (__attribute__((address_space(3))) void*)l, 16, 0, 0);
}

static __device__ __forceinline__ unsigned int packq(float a, float b, float c, float d) {
  const int ia = (int)rintf(fminf(fmaxf(a, -127.f), 127.f));
  const int ib = (int)rintf(fminf(fmaxf(b, -127.f), 127.f));
  const int ic = (int)rintf(fminf(fmaxf(c, -127.f), 127.f));
  const int id = (int)rintf(fminf(fmaxf(d, -127.f), 127.f));
  return (ia & 255) | ((ib & 255) << 8) | ((ic & 255) << 16) | ((id & 255) << 24);
}

// ---- kernel 1: blocks 0..255: xA + rowmax -> sx, Xq lora cols + pad.
//      blocks 256..1279: Wq = quantized NF4 dequant (per-row scale wr) + lora B cols (sl).
__global__ __launch_bounds__(256) void k_prep1(const float* __restrict__ x,
                                               const float* __restrict__ A,
                                               const int* __restrict__ q,
                                               const float* __restrict__ absmax,
                                               const float* __restrict__ cb,
                                               const float* __restrict__ B,
                                               signed char* __restrict__ Xq,
                                               signed char* __restrict__ Wq,
                                               float* __restrict__ sx,
                                               float* __restrict__ wr,
                                               float* __restrict__ sl) {
  const int lane = threadIdx.x & 63;
  const int wave = threadIdx.x >> 6;
  const int bid  = blockIdx.x;

  if (bid < 256) {
    const int m0 = bid * 16 + wave * 4;
    float p[4][16], mx[4];
#pragma unroll
    for (int a = 0; a < 4; ++a) {
      mx[a] = 0.f;
#pragma unroll
      for (int r = 0; r < 16; ++r) p[a][r] = 0.f;
    }
    for (int k = lane; k < INF; k += 64) {
      const float4* a4 = (const float4*)&A[(size_t)k * RANKD];
      float av[16];
      *(float4*)&av[0]  = a4[0];
      *(float4*)&av[4]  = a4[1];
      *(float4*)&av[8]  = a4[2];
      *(float4*)&av[12] = a4[3];
#pragma unroll
      for (int rr = 0; rr < 4; ++rr) {
        const float xv = x[(size_t)(m0 + rr) * INF + k];
        mx[rr] = fmaxf(mx[rr], fabsf(xv));
#pragma unroll
        for (int r = 0; r < 16; ++r) p[rr][r] = fmaf(xv, av[r], p[rr][r]);
      }
    }
#pragma unroll
    for (int rr = 0; rr < 4; ++rr) {
#pragma unroll
      for (int r = 0; r < 16; ++r) {
        float v = p[rr][r];
        v += __shfl_xor(v, 1);  v += __shfl_xor(v, 2);
        v += __shfl_xor(v, 4);  v += __shfl_xor(v, 8);
        v += __shfl_xor(v, 16); v += __shfl_xor(v, 32);
        p[rr][r] = v;
      }
      float m = mx[rr];
      m = fmaxf(m, __shfl_xor(m, 1));  m = fmaxf(m, __shfl_xor(m, 2));
      m = fmaxf(m, __shfl_xor(m, 4));  m = fmaxf(m, __shfl_xor(m, 8));
      m = fmaxf(m, __shfl_xor(m, 16)); m = fmaxf(m, __shfl_xor(m, 32));
      mx[rr] = m;
    }
    if (lane == 0) {
#pragma unroll
      for (int rr = 0; rr < 4; ++rr) {
        const float s = fmaxf(mx[rr], 1e-30f) / 127.f;
        sx[m0 + rr] = s;
        const float is4 = 1.f / (4.f * s);     // lora x-side = rint(xA/(4*sx))
        signed char* dst = Xq + (size_t)(m0 + rr) * KE + INF;
        uint4 w;
        w.x = packq(p[rr][0] * is4,  p[rr][1] * is4,  p[rr][2] * is4,  p[rr][3] * is4);
        w.y = packq(p[rr][4] * is4,  p[rr][5] * is4,  p[rr][6] * is4,  p[rr][7] * is4);
        w.z = packq(p[rr][8] * is4,  p[rr][9] * is4,  p[rr][10] * is4, p[rr][11] * is4);
        w.w = packq(p[rr][12] * is4, p[rr][13] * is4, p[rr][14] * is4, p[rr][15] * is4);
        const uint4 z = {0u, 0u, 0u, 0u};
        *(uint4*)(dst + 0)  = w;
        *(uint4*)(dst + 16) = z;
        *(uint4*)(dst + 32) = z;
        *(uint4*)(dst + 48) = z;
      }
    }
  } else {
    __shared__ float cbs[16];
    if (threadIdx.x < 16) cbs[threadIdx.x] = cb[threadIdx.x];
    __syncthreads();
    const int o = (bid - 256) * 4 + wave;
    float am = absmax[(size_t)o * 64 + lane];
    am = fmaxf(am, __shfl_xor(am, 1));  am = fmaxf(am, __shfl_xor(am, 2));
    am = fmaxf(am, __shfl_xor(am, 4));  am = fmaxf(am, __shfl_xor(am, 8));
    am = fmaxf(am, __shfl_xor(am, 16)); am = fmaxf(am, __shfl_xor(am, 32));
    const float amx = fmaxf(am, 1e-30f);
    const float qs  = 127.f / amx;            // Wq = rint(cb*am * qs)
    if (lane == 0) wr[o] = amx / 127.f;
#pragma unroll
    for (int it = 0; it < 8; ++it) {
      const int k0 = it * 512 + lane * 8;
      const int4 q0 = *(const int4*)&q[(size_t)o * INF + k0];
      const int4 q1 = *(const int4*)&q[(size_t)o * INF + k0 + 4];
      const float f = absmax[(size_t)o * 64 + (k0 >> 6)] * qs;
      uint2 w;
      w.x = packq(cbs[q0.x] * f, cbs[q0.y] * f, cbs[q0.z] * f, cbs[q0.w] * f);
      w.y = packq(cbs[q1.x] * f, cbs[q1.y] * f, cbs[q1.z] * f, cbs[q1.w] * f);
      *(uint2*)&Wq[(size_t)o * KE + k0] = w;
    }
    const float bv = (lane < 16) ? B[(size_t)lane * OUTF + o] : 0.f;
    float ab = fabsf(bv);
    ab = fmaxf(ab, __shfl_xor(ab, 1)); ab = fmaxf(ab, __shfl_xor(ab, 2));
    ab = fmaxf(ab, __shfl_xor(ab, 4)); ab = fmaxf(ab, __shfl_xor(ab, 8));
    const float sB = fmaxf(ab, 1e-30f) / 127.f;   // valid on lanes 0..15
    if (lane == 0) sl[o] = 8.f * sB;
    signed char* dst = Wq + (size_t)o * KE + INF;
    if (lane < 16) dst[lane] = (signed char)(int)rintf(bv / sB);
    else dst[lane] = 0;
  }
}

// ---- kernel 2: Xq main cols = rint(x / sx[m]) ----
__global__ __launch_bounds__(256) void k_prep2(const float* __restrict__ x,
                                               const float* __restrict__ sx,
                                               signed char* __restrict__ Xq) {
  const int lane = threadIdx.x & 63;
  const int wave = threadIdx.x >> 6;
  const int m = blockIdx.x * 4 + wave;
  const float inv = 1.f / sx[m];
#pragma unroll
  for (int it = 0; it < 8; ++it) {
    const int k0 = it * 512 + lane * 8;
    const float4 v0 = *(const float4*)&x[(size_t)m * INF + k0];
    const float4 v1 = *(const float4*)&x[(size_t)m * INF + k0 + 4];
    uint2 w;
    w.x = packq(v0.x * inv, v0.y * inv, v0.z * inv, v0.w * inv);
    w.y = packq(v1.x * inv, v1.y * inv, v1.z * inv, v1.w * inv);
    *(uint2*)&Xq[(size_t)m * KE + k0] = w;
  }
}

// ---------------- kernel 3: i8 GEMM with wave-parity role-split ----------------
// 256x256 tile, BK=64 (mfma_i32_16x16x64_i8), 8 waves (2Mx4N), ring-4 LDS.
// Register-pipelined one window ahead: window T = parity{ [odd] read(T+1) then
// MFMA(T) | [even] MFMA(T) then read(T+1) }; STAGE(T+3); vmcnt(4); bar.
// At any instant one wave/SIMD-pair feeds LDS pipe, the other the MFMA pipe.
__global__ __launch_bounds__(512, 2) void k_gemm(const signed char* __restrict__ Xq,
                                                 const signed char* __restrict__ Wq,
                                                 const float* __restrict__ bias,
                                                 const float* __restrict__ sx,
                                                 const float* __restrict__ wr,
                                                 const float* __restrict__ sl,
                                                 float* __restrict__ out) {
  extern __shared__ unsigned char LDS[];   // 4 slots x (A 16KB + B 16KB) = 128 KB
  const char* LB = (const char*)LDS;

  const int tid  = threadIdx.x;
  const int lane = tid & 63;
  const int wave = tid >> 6;        // 0..7
  const int waveM = wave >> 2;      // 0..1 -> rows [waveM*128, +128)
  const int waveN = wave & 3;       // 0..3 -> cols [waveN*64, +64)
  const int par  = wave & 1;        // parity for role-split

  // XCD chunking: 256 wgs, 32 per XCD as 4 tile-rows x 8 tile-cols (bijective)
  const int wg   = blockIdx.x;
  const int xcd  = wg & 7;
  const int loc  = wg >> 3;
  const int trB  = ((xcd & 3) * 4 + (loc >> 3)) * 256;
  const int tcB  = ((xcd >> 2) * 8 + (loc & 7)) * 256;

  // ---- staging (linear LDS dest, pre-swizzled global source); rows = 64 B ----
  const int srow = lane >> 2;                                    // 0..15
  const int wb   = ((lane & 3) * 16) ^ (((lane >> 3) & 3) << 4); // byte in row
  const signed char* gA0 = Xq + (size_t)(trB + wave * 32 + srow) * KE + wb;
  const signed char* gA1 = gA0 + (size_t)16 * KE;
  const signed char* gB0 = Wq + (size_t)(tcB + wave * 32 + srow) * KE + wb;
  const signed char* gB1 = gB0 + (size_t)16 * KE;
  const int dA0 = wave * 2048;            // byte offsets within slot
  const int dA1 = wave * 2048 + 1024;
  const int dB0 = 16384 + wave * 2048;
  const int dB1 = 16384 + wave * 2048 + 1024;

  // ---- fragment reads: row=lane&15, k-quarter=(lane>>4)*16B, XOR swizzle ----
  const int fr   = lane & 15;
  const int kq16 = (lane >> 4) * 16;
  const int sw   = ((fr >> 1) & 3) << 4;
  const int aoff = (waveM * 128 + fr) * 64 + (kq16 ^ sw);
  const int boff = 16384 + (waveN * 64 + fr) * 64 + (kq16 ^ sw);

  i32x4 acc[8][4];
#pragma unroll
  for (int i = 0; i < 8; ++i)
#pragma unroll
    for (int j = 0; j < 4; ++j) acc[i][j] = i32x4{0, 0, 0, 0};

#define STAGE(t)                                                        \
  {                                                                     \
    const int sb_ = ((t) & 3) * 32768;                                  \
    const int k0_ = (t) * 64;                                           \
    gload_lds16(gA0 + k0_, LDS + sb_ + dA0);                            \
    gload_lds16(gA1 + k0_, LDS + sb_ + dA1);                            \
    gload_lds16(gB0 + k0_, LDS + sb_ + dB0);                            \
    gload_lds16(gB1 + k0_, LDS + sb_ + dB1);                            \
  }

  i32x4 a[8], b[4], aN[8], bN[4];

#define RD0(base_)                                                      \
  {                                                                     \
    _Pragma("unroll")                                                   \
    for (int i = 0; i < 8; ++i)                                         \
      a[i] = *(const i32x4*)((base_) + aoff + i * 1024);                \
    _Pragma("unroll")                                                   \
    for (int j = 0; j < 4; ++j)                                         \
      b[j] = *(const i32x4*)((base_) + boff + j * 1024);                \
  }
#define RDN(base_)                                                      \
  {                                                                     \
    _Pragma("unroll")                                                   \
    for (int i = 0; i < 8; ++i)                                         \
      aN[i] = *(const i32x4*)((base_) + aoff + i * 1024);               \
    _Pragma("unroll")                                                   \
    for (int j = 0; j < 4; ++j)                                         \
      bN[j] = *(const i32x4*)((base_) + boff + j * 1024);               \
  }
#define MMA()                                                           \
  {                                                                     \
    __builtin_amdgcn_s_setprio(1);                                      \
    _Pragma("unroll")                                                   \
    for (int i = 0; i < 8; ++i)                                         \
      _Pragma("unroll")                                                 \
      for (int j = 0; j < 4; ++j)                                       \
        acc[i][j] = __builtin_amdgcn_mfma_i32_16x16x64_i8(a[i], b[j],   \
                                                          acc[i][j], 0, 0, 0); \
    __builtin_amdgcn_s_setprio(0);                                      \
  }
#define COPY()                                                          \
  {                                                                     \
    _Pragma("unroll")                                                   \
    for (int i = 0; i < 8; ++i) a[i] = aN[i];                           \
    _Pragma("unroll")                                                   \
    for (int j = 0; j < 4; ++j) b[j] = bN[j];                           \
  }

  // prologue: stage tiles 0,1,2; tiles 0,1 landed; read tile 0 frags
  STAGE(0)
  STAGE(1)
  STAGE(2)
  VMCNT(4);
  BAR; SCHED0;
  RD0(LB)

  // windows 0..61: parity role-split; STAGE(T+3); vmcnt(4); bar
#pragma unroll 2
  for (int T = 0; T < 62; ++T) {
    const char* baseN = LB + ((T + 1) & 3) * 32768;
    if (par) {
      RDN(baseN)
      STAGE(T + 3)
      MMA()
    } else {
      MMA()
      STAGE(T + 3)
      RDN(baseN)
    }
    COPY()
    VMCNT(4);   // retires S(T+2); S(T+3) stays in flight
    BAR; SCHED0;
  }

  // window 62: no stage; vmcnt(0) -> S(64) (lora tile) lands
  {
    const char* baseN = LB + (63 & 3) * 32768;
    if (par) { RDN(baseN) MMA() } else { MMA() RDN(baseN) }
    COPY()
    VMCNT(0);
    BAR; SCHED0;
  }
  // window 63: last main tile
  MMA()
#undef STAGE

  // ---- epilogue: lora tile 64 from slot 0 + combined scaling ----
  i32x4 aL[8], bL[4];
#pragma unroll
  for (int i = 0; i < 8; ++i)
    aL[i] = *(const i32x4*)(LB + aoff + i * 1024);
#pragma unroll
  for (int j = 0; j < 4; ++j)
    bL[j] = *(const i32x4*)(LB + boff + j * 1024);

  const int rq = (lane >> 4) * 4;
#pragma unroll
  for (int j = 0; j < 4; ++j) {
    const int n = tcB + waveN * 64 + j * 16 + fr;
    const float wrn = wr[n];
    const float sln = sl[n];
    const float bsn = bias[n];
#pragma unroll
    for (int i = 0; i < 8; ++i) {
      const i32x4 zz = {0, 0, 0, 0};
      const i32x4 t = __builtin_amdgcn_mfma_i32_16x16x64_i8(aL[i], bL[j], zz, 0, 0, 0);
      const int m0v = trB + waveM * 128 + i * 16 + rq;
      const float4 s4 = *(const float4*)&sx[m0v];
      const float* sp = (const float*)&s4;
#pragma unroll
      for (int e = 0; e < 4; ++e) {
        const float v = ((float)acc[i][j][e] * wrn + (float)t[e] * sln) * sp[e] + bsn;
        out[(size_t)(m0v + e) * OUTF + n] = v;
      }
    }
  }
#undef RD0
#undef RDN
#undef MMA
#undef COPY
}

extern "C" void kernel_launch(void* const* d_in, const int* in_sizes, int n_in,
                              void* d_out, int out_size, void* d_ws, size_t ws_size,
                              hipStream_t stream) {
  const float* x      = (const float*)d_in[0];
  const int*   q      = (const int*)d_in[1];
  const float* absmax = (const float*)d_in[2];
  const float* cb     = (const float*)d_in[3];
  const float* bias   = (const float*)d_in[4];
  const float* A      = (const float*)d_in[5];
  const float* B      = (const float*)d_in[6];
  float* out = (float*)d_out;

  signed char* Xq = (signed char*)d_ws;                       // 4096*4160 B
  signed char* Wq = Xq + (size_t)TOK * KE;                    // 4096*4160 B
  float* sx = (float*)(Wq + (size_t)OUTF * KE);               // 4096 f32
  float* wr = sx + TOK;                                       // 4096 f32
  float* sl = wr + OUTF;                                      // 4096 f32

  hipFuncSetAttribute((const void*)k_gemm,
                      hipFuncAttributeMaxDynamicSharedMemorySize, 131072);

  k_prep1<<<1280, 256, 0, stream>>>(x, A, q, absmax, cb, B, Xq, Wq, sx, wr, sl);
  k_prep2<<<1024, 256, 0, stream>>>(x, sx, Xq);
  k_gemm<<<256, 512, 131072, stream>>>(Xq, Wq, bias, sx, wr, sl, out);
}

// Round 14
// 144.802 us; speedup vs baseline: 5.6008x; 5.6008x over previous
//
#include <hip/hip_runtime.h>
#include <hip/hip_bf16.h>

typedef __attribute__((ext_vector_type(4))) int i32x4;

#define TOK   4096
#define OUTF  4096
#define INF   4096
#define KE    4160   // 4096 main + 64 lora block (16 used + 48 zero) -> 65 K-tiles of 64
#define NT    65
#define RANKD 16

#define VMCNT(n) asm volatile("s_waitcnt vmcnt(" #n ")" ::: "memory")
#define SCHED0   __builtin_amdgcn_sched_barrier(0)
#define BAR      __builtin_amdgcn_s_barrier()

static __device__ __forceinline__ void gload_lds16(const void* g, void* l) {
  __builtin_amdgcn_global_load_lds(
      (const __attribute__((address_space(1))) void*)g,
      (__attribute__((address_space(3))) void*)l, 16, 0, 0);
}

static __device__ __forceinline__ unsigned int packq(float a, float b, float c, float d) {
  const int ia = (int)rintf(fminf(fmaxf(a, -127.f), 127.f));
  const int ib = (int)rintf(fminf(fmaxf(b, -127.f), 127.f));
  const int ic = (int)rintf(fminf(fmaxf(c, -127.f), 127.f));
  const int id = (int)rintf(fminf(fmaxf(d, -127.f), 127.f));
  return (ia & 255) | ((ib & 255) << 8) | ((ic & 255) << 16) | ((id & 255) << 24);
}

// ---- kernel 1 (fused prep, 3 INDEPENDENT segments, one launch):
//   blocks    0..255 : xA = x@A -> Xq lora cols (scale slx[m]=max|xA|/127) + pad
//   blocks 256..1279 : Wq = NF4 dequant-quantize (wr[o]) + lora B cols (sl[o]=2*sB)
//   blocks 1280..2303: Xq main = rint(x/sx), sx[m]=rowmax/127 computed in-register
__global__ __launch_bounds__(256) void k_prep(const float* __restrict__ x,
                                              const float* __restrict__ A,
                                              const int* __restrict__ q,
                                              const float* __restrict__ absmax,
                                              const float* __restrict__ cb,
                                              const float* __restrict__ B,
                                              signed char* __restrict__ Xq,
                                              signed char* __restrict__ Wq,
                                              float* __restrict__ sx,
                                              float* __restrict__ slx,
                                              float* __restrict__ wr,
                                              float* __restrict__ sl) {
  const int lane = threadIdx.x & 63;
  const int wave = threadIdx.x >> 6;
  const int bid  = blockIdx.x;

  if (bid < 256) {
    // ---------- xA segment: 16 rows/block, 4 rows/wave ----------
    const int m0 = bid * 16 + wave * 4;
    float p[4][16];
#pragma unroll
    for (int a = 0; a < 4; ++a)
#pragma unroll
      for (int r = 0; r < 16; ++r) p[a][r] = 0.f;

    for (int k = lane; k < INF; k += 64) {
      const float4* a4 = (const float4*)&A[(size_t)k * RANKD];
      float av[16];
      *(float4*)&av[0]  = a4[0];
      *(float4*)&av[4]  = a4[1];
      *(float4*)&av[8]  = a4[2];
      *(float4*)&av[12] = a4[3];
#pragma unroll
      for (int rr = 0; rr < 4; ++rr) {
        const float xv = x[(size_t)(m0 + rr) * INF + k];
#pragma unroll
        for (int r = 0; r < 16; ++r) p[rr][r] = fmaf(xv, av[r], p[rr][r]);
      }
    }
#pragma unroll
    for (int rr = 0; rr < 4; ++rr)
#pragma unroll
      for (int r = 0; r < 16; ++r) {
        float v = p[rr][r];
        v += __shfl_xor(v, 1);  v += __shfl_xor(v, 2);
        v += __shfl_xor(v, 4);  v += __shfl_xor(v, 8);
        v += __shfl_xor(v, 16); v += __shfl_xor(v, 32);
        p[rr][r] = v;
      }
    if (lane == 0) {
#pragma unroll
      for (int rr = 0; rr < 4; ++rr) {
        float mx = 0.f;
#pragma unroll
        for (int r = 0; r < 16; ++r) mx = fmaxf(mx, fabsf(p[rr][r]));
        const float s = fmaxf(mx, 1e-30f) / 127.f;
        slx[m0 + rr] = s;
        const float inv = 1.f / s;
        signed char* dst = Xq + (size_t)(m0 + rr) * KE + INF;
        uint4 w;
        w.x = packq(p[rr][0] * inv,  p[rr][1] * inv,  p[rr][2] * inv,  p[rr][3] * inv);
        w.y = packq(p[rr][4] * inv,  p[rr][5] * inv,  p[rr][6] * inv,  p[rr][7] * inv);
        w.z = packq(p[rr][8] * inv,  p[rr][9] * inv,  p[rr][10] * inv, p[rr][11] * inv);
        w.w = packq(p[rr][12] * inv, p[rr][13] * inv, p[rr][14] * inv, p[rr][15] * inv);
        const uint4 z = {0u, 0u, 0u, 0u};
        *(uint4*)(dst + 0)  = w;
        *(uint4*)(dst + 16) = z;
        *(uint4*)(dst + 32) = z;
        *(uint4*)(dst + 48) = z;
      }
    }
  } else if (bid < 1280) {
    // ---------- Wq segment: 4 rows/block ----------
    __shared__ float cbs[16];
    if (threadIdx.x < 16) cbs[threadIdx.x] = cb[threadIdx.x];
    __syncthreads();
    const int o = (bid - 256) * 4 + wave;
    float am = absmax[(size_t)o * 64 + lane];
    am = fmaxf(am, __shfl_xor(am, 1));  am = fmaxf(am, __shfl_xor(am, 2));
    am = fmaxf(am, __shfl_xor(am, 4));  am = fmaxf(am, __shfl_xor(am, 8));
    am = fmaxf(am, __shfl_xor(am, 16)); am = fmaxf(am, __shfl_xor(am, 32));
    const float amx = fmaxf(am, 1e-30f);
    const float qs  = 127.f / amx;
    if (lane == 0) wr[o] = amx / 127.f;
#pragma unroll
    for (int it = 0; it < 8; ++it) {
      const int k0 = it * 512 + lane * 8;
      const int4 q0 = *(const int4*)&q[(size_t)o * INF + k0];
      const int4 q1 = *(const int4*)&q[(size_t)o * INF + k0 + 4];
      const float f = absmax[(size_t)o * 64 + (k0 >> 6)] * qs;
      uint2 w;
      w.x = packq(cbs[q0.x] * f, cbs[q0.y] * f, cbs[q0.z] * f, cbs[q0.w] * f);
      w.y = packq(cbs[q1.x] * f, cbs[q1.y] * f, cbs[q1.z] * f, cbs[q1.w] * f);
      *(uint2*)&Wq[(size_t)o * KE + k0] = w;
    }
    const float bv = (lane < 16) ? B[(size_t)lane * OUTF + o] : 0.f;
    float ab = fabsf(bv);
    ab = fmaxf(ab, __shfl_xor(ab, 1)); ab = fmaxf(ab, __shfl_xor(ab, 2));
    ab = fmaxf(ab, __shfl_xor(ab, 4)); ab = fmaxf(ab, __shfl_xor(ab, 8));
    const float sB = fmaxf(ab, 1e-30f) / 127.f;   // valid on lanes 0..15
    if (lane == 0) sl[o] = 2.f * sB;              // lora scale (factor 2 = SCALING)
    signed char* dst = Wq + (size_t)o * KE + INF;
    if (lane < 16) dst[lane] = (signed char)(int)rintf(bv / sB);
    else dst[lane] = 0;
  } else {
    // ---------- Xq main segment: 4 rows/block, 1 row/wave, x cached in regs ----------
    const int m = (bid - 1280) * 4 + wave;
    float4 v[16];
    float mx = 0.f;
#pragma unroll
    for (int it = 0; it < 16; ++it) {
      v[it] = *(const float4*)&x[(size_t)m * INF + it * 256 + lane * 4];
      mx = fmaxf(mx, fmaxf(fmaxf(fabsf(v[it].x), fabsf(v[it].y)),
                           fmaxf(fabsf(v[it].z), fabsf(v[it].w))));
    }
    mx = fmaxf(mx, __shfl_xor(mx, 1));  mx = fmaxf(mx, __shfl_xor(mx, 2));
    mx = fmaxf(mx, __shfl_xor(mx, 4));  mx = fmaxf(mx, __shfl_xor(mx, 8));
    mx = fmaxf(mx, __shfl_xor(mx, 16)); mx = fmaxf(mx, __shfl_xor(mx, 32));
    const float s = fmaxf(mx, 1e-30f) / 127.f;
    if (lane == 0) sx[m] = s;
    const float inv = 1.f / s;
#pragma unroll
    for (int it = 0; it < 16; ++it) {
      const unsigned int w = packq(v[it].x * inv, v[it].y * inv,
                                   v[it].z * inv, v[it].w * inv);
      *(unsigned int*)&Xq[(size_t)m * KE + it * 256 + lane * 4] = w;
    }
  }
}

// ---------------- kernel 2: i8 GEMM (r12 verbatim) + dual-scale epilogue ----
// 256x256 tile, BK=64 (mfma_i32_16x16x64_i8), 8 waves (2Mx4N), ring-4 LDS
// (4 x 32KB = 128 KB): {read 12 frags(T); STAGE(T+2); 32 MFMA; vmcnt(4); bar}.
// out = sx[m]*wr[n]*main + slx[m]*sl[n]*lora + bias.
__global__ __launch_bounds__(512, 2) void k_gemm(const signed char* __restrict__ Xq,
                                                 const signed char* __restrict__ Wq,
                                                 const float* __restrict__ bias,
                                                 const float* __restrict__ sx,
                                                 const float* __restrict__ slx,
                                                 const float* __restrict__ wr,
                                                 const float* __restrict__ sl,
                                                 float* __restrict__ out) {
  extern __shared__ unsigned char LDS[];   // 4 slots x (A 16KB + B 16KB) = 128 KB
  const char* LB = (const char*)LDS;

  const int tid  = threadIdx.x;
  const int lane = tid & 63;
  const int wave = tid >> 6;        // 0..7
  const int waveM = wave >> 2;      // 0..1 -> rows [waveM*128, +128)
  const int waveN = wave & 3;       // 0..3 -> cols [waveN*64, +64)

  // XCD chunking: 256 wgs, 32 per XCD as 4 tile-rows x 8 tile-cols (bijective)
  const int wg   = blockIdx.x;
  const int xcd  = wg & 7;
  const int loc  = wg >> 3;
  const int trB  = ((xcd & 3) * 4 + (loc >> 3)) * 256;
  const int tcB  = ((xcd >> 2) * 8 + (loc & 7)) * 256;

  // ---- staging (linear LDS dest, pre-swizzled global source); rows = 64 B ----
  const int srow = lane >> 2;                                    // 0..15
  const int wb   = ((lane & 3) * 16) ^ (((lane >> 3) & 3) << 4); // byte in row
  const signed char* gA0 = Xq + (size_t)(trB + wave * 32 + srow) * KE + wb;
  const signed char* gA1 = gA0 + (size_t)16 * KE;
  const signed char* gB0 = Wq + (size_t)(tcB + wave * 32 + srow) * KE + wb;
  const signed char* gB1 = gB0 + (size_t)16 * KE;
  const int dA0 = wave * 2048;            // byte offsets within slot
  const int dA1 = wave * 2048 + 1024;
  const int dB0 = 16384 + wave * 2048;
  const int dB1 = 16384 + wave * 2048 + 1024;

  // ---- fragment reads: row=lane&15, k-quarter=(lane>>4)*16B, XOR swizzle ----
  const int fr   = lane & 15;
  const int kq16 = (lane >> 4) * 16;
  const int sw   = ((fr >> 1) & 3) << 4;
  const int aoff = (waveM * 128 + fr) * 64 + (kq16 ^ sw);
  const int boff = 16384 + (waveN * 64 + fr) * 64 + (kq16 ^ sw);

  i32x4 acc[8][4];
#pragma unroll
  for (int i = 0; i < 8; ++i)
#pragma unroll
    for (int j = 0; j < 4; ++j) acc[i][j] = i32x4{0, 0, 0, 0};

#define STAGE(t)                                                        \
  {                                                                     \
    const int sb_ = ((t) & 3) * 32768;                                  \
    const int k0_ = (t) * 64;                                           \
    gload_lds16(gA0 + k0_, LDS + sb_ + dA0);                            \
    gload_lds16(gA1 + k0_, LDS + sb_ + dA1);                            \
    gload_lds16(gB0 + k0_, LDS + sb_ + dB0);                            \
    gload_lds16(gB1 + k0_, LDS + sb_ + dB1);                            \
  }

  STAGE(0)
  STAGE(1)
  VMCNT(4);
  BAR; SCHED0;

  i32x4 a[8], b[4];

  for (int T = 0; T < NT - 2; ++T) {   // T = 0..62; stages up to tile 64
    const char* base = LB + (T & 3) * 32768;
#pragma unroll
    for (int i = 0; i < 8; ++i)
      a[i] = *(const i32x4*)(base + aoff + i * 1024);
#pragma unroll
    for (int j = 0; j < 4; ++j)
      b[j] = *(const i32x4*)(base + boff + j * 1024);
    STAGE(T + 2)
    __builtin_amdgcn_s_setprio(1);
#pragma unroll
    for (int i = 0; i < 8; ++i)
#pragma unroll
      for (int j = 0; j < 4; ++j)
        acc[i][j] = __builtin_amdgcn_mfma_i32_16x16x64_i8(a[i], b[j], acc[i][j], 0, 0, 0);
    __builtin_amdgcn_s_setprio(0);
    VMCNT(4);   // retire tile T+1's stage; T+2's stays in flight
    BAR; SCHED0;
  }

  // peel T = 63 (slot 3): last main tile; then publish tile 64
  {
    const char* base = LB + 3 * 32768;
#pragma unroll
    for (int i = 0; i < 8; ++i)
      a[i] = *(const i32x4*)(base + aoff + i * 1024);
#pragma unroll
    for (int j = 0; j < 4; ++j)
      b[j] = *(const i32x4*)(base + boff + j * 1024);
    __builtin_amdgcn_s_setprio(1);
#pragma unroll
    for (int i = 0; i < 8; ++i)
#pragma unroll
      for (int j = 0; j < 4; ++j)
        acc[i][j] = __builtin_amdgcn_mfma_i32_16x16x64_i8(a[i], b[j], acc[i][j], 0, 0, 0);
    __builtin_amdgcn_s_setprio(0);
    VMCNT(0);   // tile 64 (lora block, slot 0) landed
    BAR; SCHED0;
  }
#undef STAGE

  // ---- epilogue: lora tile 64 from slot 0 + dual-scale combine ----
  i32x4 aL[8], bL[4];
#pragma unroll
  for (int i = 0; i < 8; ++i)
    aL[i] = *(const i32x4*)(LB + aoff + i * 1024);
#pragma unroll
  for (int j = 0; j < 4; ++j)
    bL[j] = *(const i32x4*)(LB + boff + j * 1024);

  const int rq = (lane >> 4) * 4;
#pragma unroll
  for (int j = 0; j < 4; ++j) {
    const int n = tcB + waveN * 64 + j * 16 + fr;
    const float wrn = wr[n];
    const float sln = sl[n];
    const float bsn = bias[n];
#pragma unroll
    for (int i = 0; i < 8; ++i) {
      const i32x4 zz = {0, 0, 0, 0};
      const i32x4 t = __builtin_amdgcn_mfma_i32_16x16x64_i8(aL[i], bL[j], zz, 0, 0, 0);
      const int m0v = trB + waveM * 128 + i * 16 + rq;
      const float4 s4  = *(const float4*)&sx[m0v];
      const float4 sl4 = *(const float4*)&slx[m0v];
      const float* sp  = (const float*)&s4;
      const float* slp = (const float*)&sl4;
#pragma unroll
      for (int e = 0; e < 4; ++e) {
        const float v = (float)acc[i][j][e] * wrn * sp[e]
                      + (float)t[e] * sln * slp[e] + bsn;
        out[(size_t)(m0v + e) * OUTF + n] = v;
      }
    }
  }
}

extern "C" void kernel_launch(void* const* d_in, const int* in_sizes, int n_in,
                              void* d_out, int out_size, void* d_ws, size_t ws_size,
                              hipStream_t stream) {
  const float* x      = (const float*)d_in[0];
  const int*   q      = (const int*)d_in[1];
  const float* absmax = (const float*)d_in[2];
  const float* cb     = (const float*)d_in[3];
  const float* bias   = (const float*)d_in[4];
  const float* A      = (const float*)d_in[5];
  const float* B      = (const float*)d_in[6];
  float* out = (float*)d_out;

  signed char* Xq = (signed char*)d_ws;                       // 4096*4160 B
  signed char* Wq = Xq + (size_t)TOK * KE;                    // 4096*4160 B
  float* sx  = (float*)(Wq + (size_t)OUTF * KE);              // 4096 f32
  float* slx = sx + TOK;                                      // 4096 f32
  float* wr  = slx + TOK;                                     // 4096 f32
  float* sl  = wr + OUTF;                                     // 4096 f32

  hipFuncSetAttribute((const void*)k_gemm,
                      hipFuncAttributeMaxDynamicSharedMemorySize, 131072);

  k_prep<<<2304, 256, 0, stream>>>(x, A, q, absmax, cb, B, Xq, Wq, sx, slx, wr, sl);
  k_gemm<<<256, 512, 131072, stream>>>(Xq, Wq, bias, sx, slx, wr, sl, out);
}